// Round 12
// baseline (451.069 us; speedup 1.0000x reference)
//
#include <hip/hip_runtime.h>
#include <math.h>

// ws layout (floats):
//   esq   : [4096]
//   state : [64*8192]   f_rest, channel-major [b][c][yx]  (== f layout)
//   fhat  : [64*8192]   [b][c][yx]
//   z     : [16384][32] pair=(v<<6|b) rows
//   psc   : [131072]    pair*NCB+cb
//   pix   : [131072] int
#define WS_ESQ   0
#define WS_STATE 4096
#define WS_FHAT  (4096 + 524288)
#define WS_Z     (4096 + 2*524288)
#define WS_PSC   (4096 + 3*524288)
#define WS_PIX   (4096 + 3*524288 + 131072)

__device__ __forceinline__ float4 v4add(float4 a, float4 b) {
    return make_float4(__fadd_rn(a.x,b.x), __fadd_rn(a.y,b.y),
                       __fadd_rn(a.z,b.z), __fadd_rn(a.w,b.w));
}
__device__ __forceinline__ float4 v4sq(float4 a) {
    return make_float4(__fmul_rn(a.x,a.x), __fmul_rn(a.y,a.y),
                       __fmul_rn(a.z,a.z), __fmul_rn(a.w,a.w));
}
// numpy pairwise sum of 32 pre-rounded squares held in 8 float4s
__device__ __forceinline__ float np_pw32(float4 q0, float4 q1, float4 q2, float4 q3,
                                         float4 q4, float4 q5, float4 q6, float4 q7) {
    float4 rA = v4add(v4add(v4add(q0, q2), q4), q6);   // r[0..3]
    float4 rB = v4add(v4add(v4add(q1, q3), q5), q7);   // r[4..7]
    float l = __fadd_rn(__fadd_rn(rA.x, rA.y), __fadd_rn(rA.z, rA.w));
    float h = __fadd_rn(__fadd_rn(rB.x, rB.y), __fadd_rn(rB.z, rB.w));
    return __fadd_rn(l, h);
}

__device__ __forceinline__ double keys64(double x) {
    // jax keys cubic (a=-0.5)
    if (x < 1.0)      return ((1.5*x - 2.5)*x)*x + 1.0;
    else if (x < 2.0) return ((-0.5*x + 2.5)*x - 4.0)*x + 2.0;
    return 0.0;
}

// Apply kernel: 512 WGs = 64 b x 8 channel-slices of 4 (+16 esq WGs at s0).
// Verbatim from validated round-9 kernel.
__global__ __launch_bounds__(256) void vq_apply(
    const float* __restrict__ f, const float* __restrict__ emb,
    float* __restrict__ esq, float* __restrict__ state, float* __restrict__ fhat,
    float* __restrict__ zws, const float* __restrict__ psc, const int* __restrict__ pix,
    int sIdx, int pn, int pnPrev, int ncbPrev)
{
    __shared__ float fr[1280];      // f_rest slice [yx*5+cc]
    __shared__ float hs[676];       // h slice [v*4+cc]
    __shared__ int   idx_arr[176];
    __shared__ float U[256];        // bicubic weights [out][in], fp64->fp32 like jax
    __shared__ float red_f[1360];
    __shared__ int   red_i[1360];

    const int tid = threadIdx.x;
    const int wg  = blockIdx.x;
    if (wg >= 512) {                // s0 only: esq WGs
        int j = ((wg - 512) << 8) + tid;
        const float4* e4 = (const float4*)(emb + (size_t)j*32);
        esq[j] = np_pw32(v4sq(e4[0]),v4sq(e4[1]),v4sq(e4[2]),v4sq(e4[3]),
                         v4sq(e4[4]),v4sq(e4[5]),v4sq(e4[6]),v4sq(e4[7]));
        return;
    }
    const int b  = wg >> 3;
    const int c0 = (wg & 7) * 4;

    // ---- P1: load f_rest slice (channel-major, coalesced) ----
    const float* src = (sIdx <= 1) ? f : state;
    for (int o = tid; o < 1024; o += 256) {
        int cc = o >> 8, yx = o & 255;
        fr[yx*5 + cc] = src[b*8192 + (c0 + cc)*256 + yx];
    }
    __syncthreads();

    if (sIdx > 0) {
        const int Vp = pnPrev * pnPrev;
        // ---- P2: combine prev partials, 2-stage (both contiguous ascending j) ----
        const int step = ncbPrev >> 3;
        for (int t = tid; t < Vp*8; t += 256) {
            int v = t >> 3, k = t & 7;
            const size_t base = (size_t)((v << 6) + b) * ncbPrev;
            float best = INFINITY; int bi = 0;
            for (int ch = k*step; ch < (k+1)*step; ++ch) {
                float sc = psc[base + ch];
                if (sc < best) { best = sc; bi = pix[base + ch]; }
            }
            red_f[t] = best; red_i[t] = bi;
        }
        __syncthreads();
        if (tid < Vp) {
            float best = INFINITY; int bi = 0;
            for (int k = 0; k < 8; ++k) {
                float sc = red_f[tid*8 + k];
                if (sc < best) { best = sc; bi = red_i[tid*8 + k]; }
            }
            idx_arr[tid] = bi;
        }
        __syncthreads();
        // ---- P3: gather h slice ----
        for (int t = tid; t < Vp*4; t += 256)
            hs[t] = emb[(size_t)idx_arr[t >> 2]*32 + c0 + (t & 3)];
        // ---- P4: bicubic weights in fp64 exactly like jax ----
        if (tid < 16) {
            double scl = 16.0 / (double)pnPrev;
            double inv = 1.0 / scl;
            double sp = ((double)tid + 0.5) * inv - 0.5;
            double w64[16]; double tot = 0.0;
            for (int q = 0; q < pnPrev; ++q) {
                double wv = keys64(fabs(sp - (double)q));
                w64[q] = wv; tot += wv;
            }
            for (int q = 0; q < pnPrev; ++q) U[tid*16 + q] = (float)(w64[q] / tot);
        }
        __syncthreads();
        // ---- P5: windowed bicubic apply, 1 thread per yx, 4 channels ----
        {
            const double inv = 1.0 / (16.0 / (double)pnPrev);
            const int yx = tid, y = yx >> 4, x = yx & 15;
            double sy = ((double)y + 0.5) * inv - 0.5;
            double sx = ((double)x + 0.5) * inv - 0.5;
            int p0 = (int)floor(sy) - 1, q0 = (int)floor(sx) - 1;
            int pa = max(0, p0), pb = min(pnPrev - 1, p0 + 3);
            int qa = max(0, q0), qb = min(pnPrev - 1, q0 + 3);
            float acc0 = 0.f, acc1 = 0.f, acc2 = 0.f, acc3 = 0.f;
            for (int p = pa; p <= pb; ++p) {
                float wy = U[y*16 + p];
                for (int q = qa; q <= qb; ++q) {
                    float wx = U[x*16 + q];
                    const float* hp = &hs[(p*pnPrev + q)*4];
                    acc0 = __fadd_rn(acc0, __fmul_rn(__fmul_rn(hp[0], wy), wx));
                    acc1 = __fadd_rn(acc1, __fmul_rn(__fmul_rn(hp[1], wy), wx));
                    acc2 = __fadd_rn(acc2, __fmul_rn(__fmul_rn(hp[2], wy), wx));
                    acc3 = __fadd_rn(acc3, __fmul_rn(__fmul_rn(hp[3], wy), wx));
                }
            }
            float a4[4] = {acc0, acc1, acc2, acc3};
            #pragma unroll
            for (int cc = 0; cc < 4; ++cc) {
                float frv = __fsub_rn(fr[yx*5 + cc], a4[cc]);
                fr[yx*5 + cc] = frv;
                int go = b*8192 + (c0 + cc)*256 + yx;
                state[go] = frv;
                fhat[go] = (sIdx == 1) ? a4[cc] : __fadd_rn(fhat[go], a4[cc]);
            }
        }
        __syncthreads();
    }

    // ---- P7: area pool (np einsum order) + z write ----
    const int V = pn * pn;
    if (pn < 16) {
        if (tid < V) {
            int p = tid / pn, q = tid - p*pn;
            int sh = (p*16)/pn, eh = ((p+1)*16 + pn - 1)/pn;
            int sw = (q*16)/pn, ew = ((q+1)*16 + pn - 1)/pn;
            float Mh = (float)(1.0/(double)(eh - sh));
            float Mw = (float)(1.0/(double)(ew - sw));
            float coef = __fmul_rn(Mh, Mw);
            float a4[4] = {0.f, 0.f, 0.f, 0.f};
            for (int hh = sh; hh < eh; ++hh)
                for (int wy = sw; wy < ew; ++wy) {
                    const float* fp = &fr[(hh*16 + wy)*5];
                    #pragma unroll
                    for (int cc = 0; cc < 4; ++cc)
                        a4[cc] = __fadd_rn(a4[cc], __fmul_rn(coef, fp[cc]));
                }
            *(float4*)(zws + (size_t)((tid << 6) + b)*32 + c0) =
                make_float4(a4[0], a4[1], a4[2], a4[3]);
        }
    } else {
        const int yx = tid;
        *(float4*)(zws + (size_t)((yx << 6) + b)*32 + c0) =
            make_float4(fr[yx*5], fr[yx*5 + 1], fr[yx*5 + 2], fr[yx*5 + 3]);
    }
}

// ---- scan helpers: named-register z fragments, asm-pinned so the compiler
// CANNOT rematerialize the loads inside the tile loop (the asm is the def) ----
#define LOADZ(P) { \
    const int pr = min((pblk << 8) + (P << 6) + lane, N - 1); \
    const float4* zp = (const float4*)(zws + (size_t)pr*32); \
    z##P##0 = zp[0]; z##P##1 = zp[1]; z##P##2 = zp[2]; z##P##3 = zp[3]; \
    z##P##4 = zp[4]; z##P##5 = zp[5]; z##P##6 = zp[6]; z##P##7 = zp[7]; \
    zsq##P = np_pw32(v4sq(z##P##0),v4sq(z##P##1),v4sq(z##P##2),v4sq(z##P##3), \
                     v4sq(z##P##4),v4sq(z##P##5),v4sq(z##P##6),v4sq(z##P##7)); }

#define PIN4(V) asm("" : "+v"(V.x), "+v"(V.y), "+v"(V.z), "+v"(V.w));
#define PINROW(P) \
    PIN4(z##P##0) PIN4(z##P##1) PIN4(z##P##2) PIN4(z##P##3) \
    PIN4(z##P##4) PIN4(z##P##5) PIN4(z##P##6) PIN4(z##P##7) \
    asm("" : "+v"(zsq##P));

#define FMA4(EV, ZA, ZB, ZC, ZD) \
    acc0 = __fmaf_rn(EV.x, ZA.x, acc0); acc1 = __fmaf_rn(EV.x, ZB.x, acc1); \
    acc2 = __fmaf_rn(EV.x, ZC.x, acc2); acc3 = __fmaf_rn(EV.x, ZD.x, acc3); \
    acc0 = __fmaf_rn(EV.y, ZA.y, acc0); acc1 = __fmaf_rn(EV.y, ZB.y, acc1); \
    acc2 = __fmaf_rn(EV.y, ZC.y, acc2); acc3 = __fmaf_rn(EV.y, ZD.y, acc3); \
    acc0 = __fmaf_rn(EV.z, ZA.z, acc0); acc1 = __fmaf_rn(EV.z, ZB.z, acc1); \
    acc2 = __fmaf_rn(EV.z, ZC.z, acc2); acc3 = __fmaf_rn(EV.z, ZD.z, acc3); \
    acc0 = __fmaf_rn(EV.w, ZA.w, acc0); acc1 = __fmaf_rn(EV.w, ZB.w, acc1); \
    acc2 = __fmaf_rn(EV.w, ZC.w, acc2); acc3 = __fmaf_rn(EV.w, ZD.w, acc3);

// Scan: 4 pairs/lane (256 pairs/WG), z pinned in 32 float4 VGPR tuples.
// emb double-buffered through LDS 64-code tiles; each b128 broadcast read
// feeds 256 FMAs. Per-acc k-ascending fma chain == BLAS order (bit-identical).
// Per-wave j ascending; cross-wave lexicographic (d,j) == numpy first-index.
__global__ __launch_bounds__(256, 2) void vq_scan(
    const float* __restrict__ emb, const float* __restrict__ esq,
    const float* __restrict__ zws, float* __restrict__ psc, int* __restrict__ pix,
    int V, int ncbMask, int ncbShift, int CB)
{
    __shared__ float ebuf[2][2048];   // 64 codes x 32
    __shared__ float esq_l[512];
    __shared__ float red_f[1024];
    __shared__ int   red_i[1024];

    const int tid  = threadIdx.x;
    const int cb   = blockIdx.x & ncbMask;
    const int pblk = blockIdx.x >> ncbShift;
    const int w    = tid >> 6, lane = tid & 63;
    const int N    = V << 6;

    float4 z00,z01,z02,z03,z04,z05,z06,z07; float zsq0;
    float4 z10,z11,z12,z13,z14,z15,z16,z17; float zsq1;
    float4 z20,z21,z22,z23,z24,z25,z26,z27; float zsq2;
    float4 z30,z31,z32,z33,z34,z35,z36,z37; float zsq3;
    LOADZ(0) LOADZ(1) LOADZ(2) LOADZ(3)
    PINROW(0) PINROW(1) PINROW(2) PINROW(3)

    const int jchunk = cb * CB;
    for (int t = tid; t < CB; t += 256) esq_l[t] = esq[jchunk + t];
    const int ntile = CB >> 6;        // CB in {64,128,256,512}

    // stage tile 0
    {
        const float4* g = (const float4*)(emb + (size_t)jchunk*32);
        for (int t = tid; t < 512; t += 256) ((float4*)ebuf[0])[t] = g[t];
    }
    __syncthreads();

    float best0 = INFINITY, best1 = INFINITY, best2 = INFINITY, best3 = INFINITY;
    int bi0 = 0, bi1 = 0, bi2 = 0, bi3 = 0;

    for (int tile = 0; tile < ntile; ++tile) {
        const int cur = tile & 1;
        if (tile + 1 < ntile) {
            const float4* g = (const float4*)(emb + (size_t)(jchunk + ((tile+1) << 6))*32);
            for (int t = tid; t < 512; t += 256) ((float4*)ebuf[cur ^ 1])[t] = g[t];
        }
        const float* eb = ebuf[cur];
        #pragma unroll 2
        for (int i = 0; i < 16; ++i) {           // wave w: codes w*16..w*16+15 (asc)
            const int lc = (w << 4) + i;
            const float4* e4 = (const float4*)(eb + lc*32);
            float acc0 = 0.f, acc1 = 0.f, acc2 = 0.f, acc3 = 0.f;
            float4 ev;
            ev = e4[0]; FMA4(ev, z00, z10, z20, z30)
            ev = e4[1]; FMA4(ev, z01, z11, z21, z31)
            ev = e4[2]; FMA4(ev, z02, z12, z22, z32)
            ev = e4[3]; FMA4(ev, z03, z13, z23, z33)
            ev = e4[4]; FMA4(ev, z04, z14, z24, z34)
            ev = e4[5]; FMA4(ev, z05, z15, z25, z35)
            ev = e4[6]; FMA4(ev, z06, z16, z26, z36)
            ev = e4[7]; FMA4(ev, z07, z17, z27, z37)
            const float sqj = esq_l[(tile << 6) + lc];
            const int j = jchunk + (tile << 6) + lc;
            float d0 = __fsub_rn(__fadd_rn(zsq0, sqj), __fmul_rn(2.0f, acc0));
            float d1 = __fsub_rn(__fadd_rn(zsq1, sqj), __fmul_rn(2.0f, acc1));
            float d2 = __fsub_rn(__fadd_rn(zsq2, sqj), __fmul_rn(2.0f, acc2));
            float d3 = __fsub_rn(__fadd_rn(zsq3, sqj), __fmul_rn(2.0f, acc3));
            if (d0 < best0) { best0 = d0; bi0 = j; }   // strict <: first-index
            if (d1 < best1) { best1 = d1; bi1 = j; }
            if (d2 < best2) { best2 = d2; bi2 = j; }
            if (d3 < best3) { best3 = d3; bi3 = j; }
        }
        __syncthreads();
    }
    red_f[w*256 + lane]       = best0;  red_i[w*256 + lane]       = bi0;
    red_f[w*256 + 64 + lane]  = best1;  red_i[w*256 + 64 + lane]  = bi1;
    red_f[w*256 + 128 + lane] = best2;  red_i[w*256 + 128 + lane] = bi2;
    red_f[w*256 + 192 + lane] = best3;  red_i[w*256 + 192 + lane] = bi3;
    __syncthreads();

    {   // cross-wave lex (d,j) reduce for this WG's 256 pairs
        const int p = (pblk << 8) + tid;
        if (p < N) {
            float bb = INFINITY; int bi = 0x7fffffff;
            #pragma unroll
            for (int ww = 0; ww < 4; ++ww) {     // wave j-ranges interleave: (d,j) lex
                float sc = red_f[ww*256 + tid];
                int   ji = red_i[ww*256 + tid];
                if (sc < bb || (sc == bb && ji < bi)) { bb = sc; bi = ji; }
            }
            psc[(size_t)p*(ncbMask + 1) + cb] = bb;
            pix[(size_t)p*(ncbMask + 1) + cb] = bi;
        }
    }
}

__global__ __launch_bounds__(256) void vq_final(
    const float* __restrict__ emb, const float* __restrict__ fhat,
    const float* __restrict__ psc, const int* __restrict__ pix,
    float* __restrict__ out)
{
    __shared__ int idx_arr[256];
    const int tid = threadIdx.x;
    const int b = blockIdx.x;
    {   // combine last scale (NCB=8) partials, ascending cb = ascending j
        float best = INFINITY; int bi = 0;
        const size_t pb0 = (size_t)((tid << 6) + b) * 8;
        for (int ch = 0; ch < 8; ++ch) {
            float sc = psc[pb0 + ch];
            if (sc < best) { best = sc; bi = pix[pb0 + ch]; }
        }
        idx_arr[tid] = bi;
    }
    __syncthreads();
    for (int o = tid; o < 8192; o += 256) {
        int c = o >> 8, yx = o & 255;
        out[b*8192 + o] = __fadd_rn(fhat[(size_t)b*8192 + o],
                                    emb[(size_t)idx_arr[yx]*32 + c]);
    }
}

extern "C" void kernel_launch(void* const* d_in, const int* in_sizes, int n_in,
                              void* d_out, int out_size, void* d_ws, size_t ws_size,
                              hipStream_t stream) {
    const float* f   = (const float*)d_in[0];
    const float* emb = (const float*)d_in[1];
    float* ws  = (float*)d_ws;
    float* out = (float*)d_out;
    float* esq   = ws + WS_ESQ;
    float* state = ws + WS_STATE;
    float* fhatp = ws + WS_FHAT;
    float* zws   = ws + WS_Z;
    float* psc   = ws + WS_PSC;
    int*   pixp  = (int*)(ws + WS_PIX);
    static const int pns[10]  = {1, 2, 3, 4, 5, 6, 8, 10, 13, 16};
    static const int ncbl[10] = {6, 6, 6, 6, 5, 5, 5, 4, 3, 3};   // log2(NCB)

    for (int s = 0; s < 10; ++s) {
        int pn = pns[s], V = pn*pn, sh = ncbl[s];
        int PB = ((V << 6) + 255) >> 8;        // pairblocks of 256 pairs
        vq_apply<<<(s == 0) ? 528 : 512, 256, 0, stream>>>(
            f, emb, esq, state, fhatp, zws, psc, pixp,
            s, pn, s > 0 ? pns[s-1] : 0, s > 0 ? (1 << ncbl[s-1]) : 0);
        vq_scan<<<PB << sh, 256, 0, stream>>>(emb, esq, zws, psc, pixp,
                                              V, (1 << sh) - 1, sh, 4096 >> sh);
    }
    vq_final<<<64, 256, 0, stream>>>(emb, fhatp, psc, pixp, out);
}

// Round 13
// 433.476 us; speedup vs baseline: 1.0406x; 1.0406x over previous
//
#include <hip/hip_runtime.h>
#include <math.h>

// ws layout (floats):
//   esq   : [4096]
//   state : [64*8192]   f_rest, channel-major [b][c][yx]  (== f layout)
//   fhat  : [64*8192]   [b][c][yx]
//   z     : [16384][32] pair=(v<<6|b) rows
//   best  : [2][16384]  u64 packed (dkey(d)<<32)|j, ping-pong by scale parity
#define WS_ESQ   0
#define WS_STATE 4096
#define WS_FHAT  (4096 + 524288)
#define WS_Z     (4096 + 2*524288)
#define WS_BEST  (4096 + 3*524288)

__device__ __forceinline__ float4 v4add(float4 a, float4 b) {
    return make_float4(__fadd_rn(a.x,b.x), __fadd_rn(a.y,b.y),
                       __fadd_rn(a.z,b.z), __fadd_rn(a.w,b.w));
}
__device__ __forceinline__ float4 v4sq(float4 a) {
    return make_float4(__fmul_rn(a.x,a.x), __fmul_rn(a.y,a.y),
                       __fmul_rn(a.z,a.z), __fmul_rn(a.w,a.w));
}
// numpy pairwise sum of 32 pre-rounded squares held in 8 float4s
__device__ __forceinline__ float np_pw32(float4 q0, float4 q1, float4 q2, float4 q3,
                                         float4 q4, float4 q5, float4 q6, float4 q7) {
    float4 rA = v4add(v4add(v4add(q0, q2), q4), q6);   // r[0..3]
    float4 rB = v4add(v4add(v4add(q1, q3), q5), q7);   // r[4..7]
    float l = __fadd_rn(__fadd_rn(rA.x, rA.y), __fadd_rn(rA.z, rA.w));
    float h = __fadd_rn(__fadd_rn(rB.x, rB.y), __fadd_rn(rB.z, rB.w));
    return __fadd_rn(l, h);
}

__device__ __forceinline__ double keys64(double x) {
    // jax keys cubic (a=-0.5)
    if (x < 1.0)      return ((1.5*x - 2.5)*x)*x + 1.0;
    else if (x < 2.0) return ((-0.5*x + 2.5)*x - 4.0)*x + 2.0;
    return 0.0;
}

// order-preserving float->uint map; d==-0.0 unreachable (RN equal-sub -> +0.0)
__device__ __forceinline__ unsigned dkey(float d) {
    unsigned b = __float_as_uint(d);
    return (b & 0x80000000u) ? ~b : (b | 0x80000000u);
}

// Apply kernel: 512 WGs = 64 b x 8 channel-slices of 4 (+16 esq WGs at s0).
// Same fp32 sequences as validated round-9 kernel; argmin combine replaced by
// direct read of the packed atomicMin result (identical first-index semantics).
__global__ __launch_bounds__(256) void vq_apply(
    const float* __restrict__ f, const float* __restrict__ emb,
    float* __restrict__ esq, float* __restrict__ state, float* __restrict__ fhat,
    float* __restrict__ zws, const unsigned long long* __restrict__ bestPrev,
    unsigned long long* __restrict__ bestCur,
    int sIdx, int pn, int pnPrev)
{
    __shared__ float fr[1280];      // f_rest slice [yx*5+cc]
    __shared__ float hs[676];       // h slice [v*4+cc]
    __shared__ int   idx_arr[176];
    __shared__ float U[256];        // bicubic weights [out][in], fp64->fp32 like jax

    const int tid = threadIdx.x;
    const int wg  = blockIdx.x;
    if (wg >= 512) {                // s0 only: esq WGs
        int j = ((wg - 512) << 8) + tid;
        const float4* e4 = (const float4*)(emb + (size_t)j*32);
        esq[j] = np_pw32(v4sq(e4[0]),v4sq(e4[1]),v4sq(e4[2]),v4sq(e4[3]),
                         v4sq(e4[4]),v4sq(e4[5]),v4sq(e4[6]),v4sq(e4[7]));
        return;
    }
    const int b  = wg >> 3;
    const int c0 = (wg & 7) * 4;

    // init this scale's best slot (32 entries per WG covers 16384)
    for (int t = tid; t < 32; t += 256) bestCur[wg*32 + t] = ~0ull;

    // ---- P1: load f_rest slice (channel-major, coalesced) ----
    const float* src = (sIdx <= 1) ? f : state;
    for (int o = tid; o < 1024; o += 256) {
        int cc = o >> 8, yx = o & 255;
        fr[yx*5 + cc] = src[b*8192 + (c0 + cc)*256 + yx];
    }
    __syncthreads();

    if (sIdx > 0) {
        const int Vp = pnPrev * pnPrev;
        // ---- P2: read prev argmin directly (packed lex-min == first index) ----
        if (tid < Vp)
            idx_arr[tid] = (int)(bestPrev[(tid << 6) + b] & 0xFFFFFFFFull);
        __syncthreads();
        // ---- P3: gather h slice ----
        for (int t = tid; t < Vp*4; t += 256)
            hs[t] = emb[(size_t)idx_arr[t >> 2]*32 + c0 + (t & 3)];
        // ---- P4: bicubic weights in fp64 exactly like jax ----
        if (tid < 16) {
            double scl = 16.0 / (double)pnPrev;
            double inv = 1.0 / scl;
            double sp = ((double)tid + 0.5) * inv - 0.5;
            double w64[16]; double tot = 0.0;
            for (int q = 0; q < pnPrev; ++q) {
                double wv = keys64(fabs(sp - (double)q));
                w64[q] = wv; tot += wv;
            }
            for (int q = 0; q < pnPrev; ++q) U[tid*16 + q] = (float)(w64[q] / tot);
        }
        __syncthreads();
        // ---- P5: windowed bicubic apply, 1 thread per yx, 4 channels ----
        {
            const double inv = 1.0 / (16.0 / (double)pnPrev);
            const int yx = tid, y = yx >> 4, x = yx & 15;
            double sy = ((double)y + 0.5) * inv - 0.5;
            double sx = ((double)x + 0.5) * inv - 0.5;
            int p0 = (int)floor(sy) - 1, q0 = (int)floor(sx) - 1;
            int pa = max(0, p0), pb = min(pnPrev - 1, p0 + 3);
            int qa = max(0, q0), qb = min(pnPrev - 1, q0 + 3);
            float acc0 = 0.f, acc1 = 0.f, acc2 = 0.f, acc3 = 0.f;
            for (int p = pa; p <= pb; ++p) {
                float wy = U[y*16 + p];
                for (int q = qa; q <= qb; ++q) {
                    float wx = U[x*16 + q];
                    const float* hp = &hs[(p*pnPrev + q)*4];
                    acc0 = __fadd_rn(acc0, __fmul_rn(__fmul_rn(hp[0], wy), wx));
                    acc1 = __fadd_rn(acc1, __fmul_rn(__fmul_rn(hp[1], wy), wx));
                    acc2 = __fadd_rn(acc2, __fmul_rn(__fmul_rn(hp[2], wy), wx));
                    acc3 = __fadd_rn(acc3, __fmul_rn(__fmul_rn(hp[3], wy), wx));
                }
            }
            float a4[4] = {acc0, acc1, acc2, acc3};
            #pragma unroll
            for (int cc = 0; cc < 4; ++cc) {
                float frv = __fsub_rn(fr[yx*5 + cc], a4[cc]);
                fr[yx*5 + cc] = frv;
                int go = b*8192 + (c0 + cc)*256 + yx;
                state[go] = frv;
                fhat[go] = (sIdx == 1) ? a4[cc] : __fadd_rn(fhat[go], a4[cc]);
            }
        }
        __syncthreads();
    }

    // ---- P7: area pool (np einsum order) + z write ----
    const int V = pn * pn;
    if (pn < 16) {
        if (tid < V) {
            int p = tid / pn, q = tid - p*pn;
            int sh = (p*16)/pn, eh = ((p+1)*16 + pn - 1)/pn;
            int sw = (q*16)/pn, ew = ((q+1)*16 + pn - 1)/pn;
            float Mh = (float)(1.0/(double)(eh - sh));
            float Mw = (float)(1.0/(double)(ew - sw));
            float coef = __fmul_rn(Mh, Mw);
            float a4[4] = {0.f, 0.f, 0.f, 0.f};
            for (int hh = sh; hh < eh; ++hh)
                for (int wy = sw; wy < ew; ++wy) {
                    const float* fp = &fr[(hh*16 + wy)*5];
                    #pragma unroll
                    for (int cc = 0; cc < 4; ++cc)
                        a4[cc] = __fadd_rn(a4[cc], __fmul_rn(coef, fp[cc]));
                }
            *(float4*)(zws + (size_t)((tid << 6) + b)*32 + c0) =
                make_float4(a4[0], a4[1], a4[2], a4[3]);
        }
    } else {
        const int yx = tid;
        *(float4*)(zws + (size_t)((yx << 6) + b)*32 + c0) =
            make_float4(fr[yx*5], fr[yx*5 + 1], fr[yx*5 + 2], fr[yx*5 + 3]);
    }
}

// ---- scan helpers: named-register z fragments ----
#define LOADZ(P) { \
    const int pr = min((pblk << 8) + (P << 6) + lane, N - 1); \
    const float4* zp = (const float4*)(zws + (size_t)pr*32); \
    z##P##0 = zp[0]; z##P##1 = zp[1]; z##P##2 = zp[2]; z##P##3 = zp[3]; \
    z##P##4 = zp[4]; z##P##5 = zp[5]; z##P##6 = zp[6]; z##P##7 = zp[7]; \
    zsq##P = np_pw32(v4sq(z##P##0),v4sq(z##P##1),v4sq(z##P##2),v4sq(z##P##3), \
                     v4sq(z##P##4),v4sq(z##P##5),v4sq(z##P##6),v4sq(z##P##7)); }

#define FMA4(EV, ZA, ZB, ZC, ZD) \
    acc0 = __fmaf_rn(EV.x, ZA.x, acc0); acc1 = __fmaf_rn(EV.x, ZB.x, acc1); \
    acc2 = __fmaf_rn(EV.x, ZC.x, acc2); acc3 = __fmaf_rn(EV.x, ZD.x, acc3); \
    acc0 = __fmaf_rn(EV.y, ZA.y, acc0); acc1 = __fmaf_rn(EV.y, ZB.y, acc1); \
    acc2 = __fmaf_rn(EV.y, ZC.y, acc2); acc3 = __fmaf_rn(EV.y, ZD.y, acc3); \
    acc0 = __fmaf_rn(EV.z, ZA.z, acc0); acc1 = __fmaf_rn(EV.z, ZB.z, acc1); \
    acc2 = __fmaf_rn(EV.z, ZC.z, acc2); acc3 = __fmaf_rn(EV.z, ZD.z, acc3); \
    acc0 = __fmaf_rn(EV.w, ZA.w, acc0); acc1 = __fmaf_rn(EV.w, ZB.w, acc1); \
    acc2 = __fmaf_rn(EV.w, ZC.w, acc2); acc3 = __fmaf_rn(EV.w, ZD.w, acc3);

// Scan: grid = PB(256-pair blocks) x 16 chunks of 256 codes. Single staging
// barrier; z (4 pairs/lane, named regs) is loaded AFTER it and live through a
// barrier-free inner loop -> no spill motivation. Waves own contiguous
// ascending 64-code blocks (strict < = first-index); WG result lands in
// best[pair] via packed-u64 atomicMin = exact lexicographic (d, j).
__global__ __launch_bounds__(256, 2) void vq_scan(
    const float* __restrict__ emb, const float* __restrict__ esq,
    const float* __restrict__ zws, unsigned long long* __restrict__ best, int N)
{
    __shared__ float ebuf[8192];      // 256 codes x 32
    __shared__ float esq_l[256];
    float* red_f = ebuf;              // overlay after inner loop (ebuf dead)
    int*   red_i = (int*)(ebuf + 1024);

    const int tid  = threadIdx.x;
    const int cb   = blockIdx.x & 15;
    const int pblk = blockIdx.x >> 4;
    const int w    = tid >> 6, lane = tid & 63;
    const int jchunk = cb << 8;

    // ---- stage the full 256-code tile + esq (one barrier) ----
    {
        const float4* g = (const float4*)(emb + (size_t)jchunk*32);
        float4* eb4 = (float4*)ebuf;
        for (int t = tid; t < 2048; t += 256) eb4[t] = g[t];
        esq_l[tid] = esq[jchunk + tid];
    }
    __syncthreads();

    // ---- z: 4 pairs/lane in named regs, loaded post-barrier ----
    float4 z00,z01,z02,z03,z04,z05,z06,z07; float zsq0;
    float4 z10,z11,z12,z13,z14,z15,z16,z17; float zsq1;
    float4 z20,z21,z22,z23,z24,z25,z26,z27; float zsq2;
    float4 z30,z31,z32,z33,z34,z35,z36,z37; float zsq3;
    LOADZ(0) LOADZ(1) LOADZ(2) LOADZ(3)

    // ---- barrier-free scan: wave w owns codes [w*64, w*64+64) ascending ----
    float best0 = INFINITY, best1 = INFINITY, best2 = INFINITY, best3 = INFINITY;
    int bi0 = 0, bi1 = 0, bi2 = 0, bi3 = 0;
    const int base = w << 6;
    for (int i = 0; i < 64; ++i) {
        const int lc = base + i;
        const float4* e4 = (const float4*)(ebuf + lc*32);
        float acc0 = 0.f, acc1 = 0.f, acc2 = 0.f, acc3 = 0.f;
        float4 ev;
        ev = e4[0]; FMA4(ev, z00, z10, z20, z30)
        ev = e4[1]; FMA4(ev, z01, z11, z21, z31)
        ev = e4[2]; FMA4(ev, z02, z12, z22, z32)
        ev = e4[3]; FMA4(ev, z03, z13, z23, z33)
        ev = e4[4]; FMA4(ev, z04, z14, z24, z34)
        ev = e4[5]; FMA4(ev, z05, z15, z25, z35)
        ev = e4[6]; FMA4(ev, z06, z16, z26, z36)
        ev = e4[7]; FMA4(ev, z07, z17, z27, z37)
        const float sqj = esq_l[lc];
        const int j = jchunk + lc;
        float d0 = __fsub_rn(__fadd_rn(zsq0, sqj), __fmul_rn(2.0f, acc0));
        float d1 = __fsub_rn(__fadd_rn(zsq1, sqj), __fmul_rn(2.0f, acc1));
        float d2 = __fsub_rn(__fadd_rn(zsq2, sqj), __fmul_rn(2.0f, acc2));
        float d3 = __fsub_rn(__fadd_rn(zsq3, sqj), __fmul_rn(2.0f, acc3));
        if (d0 < best0) { best0 = d0; bi0 = j; }   // strict <: first-index
        if (d1 < best1) { best1 = d1; bi1 = j; }
        if (d2 < best2) { best2 = d2; bi2 = j; }
        if (d3 < best3) { best3 = d3; bi3 = j; }
    }
    __syncthreads();   // all waves done reading ebuf -> overlay as red_f/red_i

    red_f[w*256 + lane]       = best0;  red_i[w*256 + lane]       = bi0;
    red_f[w*256 + 64 + lane]  = best1;  red_i[w*256 + 64 + lane]  = bi1;
    red_f[w*256 + 128 + lane] = best2;  red_i[w*256 + 128 + lane] = bi2;
    red_f[w*256 + 192 + lane] = best3;  red_i[w*256 + 192 + lane] = bi3;
    __syncthreads();

    {   // cross-wave: ascending wave = ascending code block -> strict <
        const int p = (pblk << 8) + tid;
        if (p < N) {
            float bb = INFINITY; int bi = 0;
            #pragma unroll
            for (int ww = 0; ww < 4; ++ww) {
                float sc = red_f[ww*256 + tid];
                if (sc < bb) { bb = sc; bi = red_i[ww*256 + tid]; }
            }
            unsigned long long pk = ((unsigned long long)dkey(bb) << 32) | (unsigned)bi;
            atomicMin(&best[p], pk);
        }
    }
}

__global__ __launch_bounds__(256) void vq_final(
    const float* __restrict__ emb, const float* __restrict__ fhat,
    const unsigned long long* __restrict__ best9, float* __restrict__ out)
{
    __shared__ int idx_arr[256];
    const int tid = threadIdx.x;
    const int b = blockIdx.x;
    idx_arr[tid] = (int)(best9[(tid << 6) + b] & 0xFFFFFFFFull);
    __syncthreads();
    for (int o = tid; o < 8192; o += 256) {
        int c = o >> 8, yx = o & 255;
        out[b*8192 + o] = __fadd_rn(fhat[(size_t)b*8192 + o],
                                    emb[(size_t)idx_arr[yx]*32 + c]);
    }
}

extern "C" void kernel_launch(void* const* d_in, const int* in_sizes, int n_in,
                              void* d_out, int out_size, void* d_ws, size_t ws_size,
                              hipStream_t stream) {
    const float* f   = (const float*)d_in[0];
    const float* emb = (const float*)d_in[1];
    float* ws  = (float*)d_ws;
    float* out = (float*)d_out;
    float* esq   = ws + WS_ESQ;
    float* state = ws + WS_STATE;
    float* fhatp = ws + WS_FHAT;
    float* zws   = ws + WS_Z;
    unsigned long long* best = (unsigned long long*)(ws + WS_BEST);
    static const int pns[10] = {1, 2, 3, 4, 5, 6, 8, 10, 13, 16};

    for (int s = 0; s < 10; ++s) {
        int pn = pns[s], V = pn*pn, N = V << 6;
        int PB = (N + 255) >> 8;
        unsigned long long* bPrev = best + (size_t)((s + 1) & 1) * 16384;
        unsigned long long* bCur  = best + (size_t)(s & 1) * 16384;
        vq_apply<<<(s == 0) ? 528 : 512, 256, 0, stream>>>(
            f, emb, esq, state, fhatp, zws, bPrev, bCur,
            s, pn, s > 0 ? pns[s-1] : 0);
        vq_scan<<<PB * 16, 256, 0, stream>>>(emb, esq, zws, bCur, N);
    }
    vq_final<<<64, 256, 0, stream>>>(emb, fhatp, best + 16384, out);
}